// Round 6
// baseline (199.557 us; speedup 1.0000x reference)
//
#include <hip/hip_runtime.h>
#include <hip/hip_bf16.h>

// HeadLayer: B=8, S=2048, E=1024, H=64.
// Inputs (fp32): x[B,S,E], Wq[E,H], Wk[E,H], Wv[E,H]. Output (fp32): [B,S,H].
// ws (frag-major bf16 intermediates; MFMA-fragment-ordered so attn loads are
// fully-coalesced 1KB wave-loads):
//   qbF: ((b*128+qt)*2+ks)*512 + lane*8 + u  = Q[qt*16+(lane&15)][ks*32+(lane>>4)*8+u] (pre-scaled 1/32)
//   kbF: (((b*64+j)*2+n2)*2+ks)*512 + lane*8 + u = K[j*32+n2*16+(lane&15)][ks*32+(lane>>4)*8+u]
//   vbF: ((b*64+j)*4+nt)*512 + lane*8 + u = V[j*32+(lane>>4)*8+u][nt*16+(lane&15)]
//   Wd: frag-direct W layout; pacc[B,S,8,H] fp32; plsum[B,S,8] fp32.

#define BATCH 8
#define SEQ   2048
#define EMB   1024
#define HD    64
#define ROWS  (BATCH*SEQ)      // 16384
#define BK    64
#define NKT   (EMB / BK)       // 16
#define NSPLIT 8

typedef __attribute__((ext_vector_type(8))) short short8;   // 8 bf16 (4 VGPR)
typedef __attribute__((ext_vector_type(4))) float floatx4;  // MFMA C/D frag

static __device__ __forceinline__ short f2bf(float f) {
  union { __hip_bfloat16 h; short s; } u;
  u.h = __float2bfloat16(f);
  return u.s;
}

static __device__ __forceinline__ short8 pack8(float4 u, float4 v) {
  short8 r;
  r[0] = f2bf(u.x); r[1] = f2bf(u.y); r[2] = f2bf(u.z); r[3] = f2bf(u.w);
  r[4] = f2bf(v.x); r[5] = f2bf(v.y); r[6] = f2bf(v.z); r[7] = f2bf(v.w);
  return r;
}

// ---------------- W pre-pass: frag-direct layout (unchanged, verified) ------
__global__ __launch_bounds__(256) void wt_kernel(
    const float* __restrict__ Wq, const float* __restrict__ Wk,
    const float* __restrict__ Wv, short* __restrict__ Wd) {
  const int id = blockIdx.x * 256 + threadIdx.x;   // 0..24575
  const int lane = id & 63;
  const int ks = (id >> 6) & 1;
  const int id2 = id >> 7;                          // kt*12 + nt
  const int nt = id2 % 12;
  const int kt = id2 / 12;
  const int lo = lane & 15, quad = lane >> 4;
  const int np = nt * 16 + lo;
  const float* __restrict__ W = (np < 64) ? Wq : ((np < 128) ? Wk : Wv);
  const int n = np & 63;
  const int k0 = kt * BK + (4 * ks + quad) * 8;
  short8 o;
#pragma unroll
  for (int u = 0; u < 8; ++u) o[u] = f2bf(W[(size_t)(k0 + u) * HD + n]);
  *(short8*)(Wd + (size_t)id * 8) = o;
}

// ---------------- MFMA QKV projection: R2 main loop (M=32), frag-major out --
__global__ __launch_bounds__(256, 2) void proj_kernel(
    const float* __restrict__ x, const short* __restrict__ Wd,
    short* __restrict__ qbF, short* __restrict__ kbF, short* __restrict__ vbF) {
  __shared__ __align__(16) short Ab[2][32 * 64];   // 8 KB bf16, XOR-swizzled

  const int t = threadIdx.x, lane = t & 63, w = t >> 6;
  const int lo = lane & 15, quad = lane >> 4;
  const int e = lo & 7;
  const int m0 = blockIdx.x * 32;

  const int srow = t >> 3, sc = t & 7;
  const float* sgp = x + (size_t)(m0 + srow) * EMB + sc * 8;
  const int sslot = srow * 64 + ((sc ^ (srow & 7)) << 3);

  const short* bgp = Wd + (size_t)(w * 3) * 1024 + lane * 8;

  floatx4 acc[2][3];
#pragma unroll
  for (int mf = 0; mf < 2; ++mf)
#pragma unroll
    for (int j = 0; j < 3; ++j) acc[mf][j] = (floatx4){0.f, 0.f, 0.f, 0.f};

  short8 bcur[3][2], bnxt[3][2];
  float4 ra, rb;

  auto LOADA = [&](int kt) {
    const float* p = sgp + kt * BK;
    ra = *(const float4*)(p);
    rb = *(const float4*)(p + 4);
  };
  auto LOAD_B = [&](short8 (&bf)[3][2], int kt) {
    const short* bg = bgp + (size_t)kt * 12288;
#pragma unroll
    for (int j = 0; j < 3; ++j)
#pragma unroll
      for (int ks = 0; ks < 2; ++ks)
        bf[j][ks] = *(const short8*)(bg + j * 1024 + ks * 512);
  };

  LOADA(0);
  LOAD_B(bcur, 0);
  *(short8*)(&Ab[0][sslot]) = pack8(ra, rb);
  __syncthreads();

  int buf = 0;
  for (int kt = 0; kt < NKT; ++kt) {
    const bool more = (kt + 1 < NKT);
    if (more) { LOADA(kt + 1); LOAD_B(bnxt, kt + 1); }
    short8 af[2][2];
#pragma unroll
    for (int mf = 0; mf < 2; ++mf)
#pragma unroll
      for (int ks = 0; ks < 2; ++ks)
        af[mf][ks] = *(const short8*)(
            &Ab[buf][(mf * 16 + lo) * 64 + (((4 * ks + quad) ^ e) << 3)]);
#pragma unroll
    for (int ks = 0; ks < 2; ++ks)
#pragma unroll
      for (int j = 0; j < 3; ++j) {
        acc[0][j] = __builtin_amdgcn_mfma_f32_16x16x32_bf16(af[0][ks], bcur[j][ks], acc[0][j], 0, 0, 0);
        acc[1][j] = __builtin_amdgcn_mfma_f32_16x16x32_bf16(af[1][ks], bcur[j][ks], acc[1][j], 0, 0, 0);
      }
    if (more) {
      *(short8*)(&Ab[buf ^ 1][sslot]) = pack8(ra, rb);
#pragma unroll
      for (int j = 0; j < 3; ++j)
#pragma unroll
        for (int ks = 0; ks < 2; ++ks) bcur[j][ks] = bnxt[j][ks];
    }
    __syncthreads();
    buf ^= 1;
  }

  // ---- epilogue: frag-major stores
  // rows: m0 + mf*16 + quad*4 + r; block-constants: bb, qts (16-row idx), jk (32-row idx)
  const int bb = m0 >> 11;
  const int s0q = m0 & (SEQ - 1);
  const int qts = s0q >> 4;       // 16-row q-tile base (mf adds 1)
  const int jk = s0q >> 5;        // 32-row key/value tile (m0 is 32-aligned)
  const int qr = quad * 4;        // row&15 base (r adds)
#pragma unroll
  for (int mf = 0; mf < 2; ++mf) {
#pragma unroll
    for (int j = 0; j < 3; ++j) {
      const int nt = w * 3 + j;
      const floatx4 v = acc[mf][j];
      if (nt < 4) {
        // Q: ((bb*128+qts+mf)*2 + (nt>>1))*512 + (qr+r + 16*((2*nt+(lo>>3))&3))*8 + (lo&7)
        short* qp = qbF + ((size_t)((bb * 128 + qts + mf) * 2 + (nt >> 1))) * 512 +
                    (qr + 16 * ((2 * nt + (lo >> 3)) & 3)) * 8 + (lo & 7);
#pragma unroll
        for (int r = 0; r < 4; ++r) qp[r * 8] = f2bf(v[r] * 0.03125f);
      } else if (nt < 8) {
        const int a = nt - 4;
        short* kp = kbF + ((size_t)(((bb * 64 + jk) * 2 + mf) * 2 + (a >> 1))) * 512 +
                    (qr + 16 * ((2 * a + (lo >> 3)) & 3)) * 8 + (lo & 7);
#pragma unroll
        for (int r = 0; r < 4; ++r) kp[r * 8] = f2bf(v[r]);
      } else {
        const int ntv = nt - 8;
        // V: L = lo + 16*(mf*2 + (quad>>1)); u0 = (quad&1)*4; contiguous short4
        short* vp = vbF + ((size_t)((bb * 64 + jk) * 4 + ntv)) * 512 +
                    (lo + 16 * (mf * 2 + (quad >> 1))) * 8 + (quad & 1) * 4;
        short4 sv = make_short4(f2bf(v[0]), f2bf(v[1]), f2bf(v[2]), f2bf(v[3]));
        *(short4*)vp = sv;
      }
    }
  }
}

// ---------------- flash attention: frag-major direct loads, no K/V LDS ------
// Wave task = (qt 16-row tile, batch, split sp: it = sp, sp+8, ...), 32-key
// steps, zero barriers. All K/V frag loads are contiguous 1KB wave-loads from
// L2-resident frag-major buffers (no gathers, no staging). Rolling register
// prefetch: kf reloaded right after QK consumes it, vf after PV. Grid
// 128qt x 2sph x 8b = 2048 blocks -> 8 blocks/CU; LDS 5KB; heavy-first;
// b = bx&7 pins batch to XCD.
#define PSTR 40

__global__ __launch_bounds__(256, 8) void attn_kernel(
    const short* __restrict__ qbF, const short* __restrict__ kbF,
    const short* __restrict__ vbF, float* __restrict__ pacc,
    float* __restrict__ plsum) {
  __shared__ __align__(16) short Ps[4][16 * PSTR];   // 5 KB total

  const int bx = blockIdx.x;                 // 0..2047
  const int qt = 127 - (bx >> 4);            // heavy first
  const int b = bx & 7;
  const int sph = ((bx >> 3) & 1) * 4;
  const int w = threadIdx.x >> 6;
  const int sp = sph + w;                    // split 0..7
  const int lane = threadIdx.x & 63;
  const int lo = lane & 15, quad = lane >> 4;
  const int q0 = qt * 16;
  const int niter = (qt >> 1) + 1;           // 32-key steps

  // Q frags: two contiguous 1KB wave-loads
  const short* qp = qbF + (size_t)((b * 128 + qt) * 2) * 512 + lane * 8;
  const short8 qf0 = *(const short8*)(qp);
  const short8 qf1 = *(const short8*)(qp + 512);

  // per-wave tile pointers (tile stride 2048 shorts = 4KB)
  const short* kp = kbF + (size_t)(b * 64 + sp) * 2048 + lane * 8;
  const short* vp = vbF + (size_t)(b * 64 + sp) * 2048 + lane * 8;

  floatx4 acc[4];
  float lsum[4] = {0.f, 0.f, 0.f, 0.f};
#pragma unroll
  for (int nt = 0; nt < 4; ++nt) acc[nt] = (floatx4){0.f, 0.f, 0.f, 0.f};

  short* Pw = Ps[w];
  const int rowq = q0 + quad * 4;

  short8 kf[2][2], vf[4];
  auto LOADK = [&]() {
#pragma unroll
    for (int n2 = 0; n2 < 2; ++n2)
#pragma unroll
      for (int ks = 0; ks < 2; ++ks)
        kf[n2][ks] = *(const short8*)(kp + (n2 * 2 + ks) * 512);
  };
  auto LOADV = [&]() {
#pragma unroll
    for (int nt = 0; nt < 4; ++nt)
      vf[nt] = *(const short8*)(vp + nt * 512);
  };

  int it = sp;
  if (it < niter) { LOADK(); LOADV(); }
  for (; it < niter; it += NSPLIT) {
    const int j0 = it * 32;
    // ---- QK^T (kf in regs)
    floatx4 s0 = (floatx4){0.f, 0.f, 0.f, 0.f};
    floatx4 s1 = (floatx4){0.f, 0.f, 0.f, 0.f};
    __builtin_amdgcn_s_setprio(1);
    s0 = __builtin_amdgcn_mfma_f32_16x16x32_bf16(qf0, kf[0][0], s0, 0, 0, 0);
    s0 = __builtin_amdgcn_mfma_f32_16x16x32_bf16(qf1, kf[0][1], s0, 0, 0, 0);
    s1 = __builtin_amdgcn_mfma_f32_16x16x32_bf16(qf0, kf[1][0], s1, 0, 0, 0);
    s1 = __builtin_amdgcn_mfma_f32_16x16x32_bf16(qf1, kf[1][1], s1, 0, 0, 0);
    __builtin_amdgcn_s_setprio(0);
    // ---- prefetch next K (kf regs free after QK issue)
    const bool more = (it + NSPLIT < niter);
    kp += NSPLIT * 2048;
    if (more) LOADK();
    // ---- softmax numerator + P to per-wave LDS
    const bool diag = (j0 + 32 > q0);
#pragma unroll
    for (int r = 0; r < 4; ++r) {
      float e0 = __expf(s0[r]);
      float e1 = __expf(s1[r]);
      if (diag) {
        e0 = (j0 + lo <= rowq + r) ? e0 : 0.f;
        e1 = (j0 + 16 + lo <= rowq + r) ? e1 : 0.f;
      }
      lsum[r] += e0 + e1;
      Pw[(quad * 4 + r) * PSTR + lo] = f2bf(e0);
      Pw[(quad * 4 + r) * PSTR + 16 + lo] = f2bf(e1);
    }
    const short8 pf = *(const short8*)(&Pw[lo * PSTR + quad * 8]);
    // ---- P·V
    __builtin_amdgcn_s_setprio(1);
#pragma unroll
    for (int nt = 0; nt < 4; ++nt)
      acc[nt] = __builtin_amdgcn_mfma_f32_16x16x32_bf16(pf, vf[nt], acc[nt], 0, 0, 0);
    __builtin_amdgcn_s_setprio(0);
    // ---- prefetch next V (vf regs free after PV issue)
    vp += NSPLIT * 2048;
    if (more) LOADV();
  }

  // row-sum over the 16 key lanes (lo bits only; quad carries q)
#pragma unroll
  for (int d = 1; d < 16; d <<= 1) {
#pragma unroll
    for (int r = 0; r < 4; ++r) lsum[r] += __shfl_xor(lsum[r], d);
  }

  // un-normalized partials out (zeros for empty splits)
#pragma unroll
  for (int nt = 0; nt < 4; ++nt) {
#pragma unroll
    for (int r = 0; r < 4; ++r)
      pacc[(((size_t)b * SEQ + rowq + r) * NSPLIT + sp) * HD + nt * 16 + lo] =
          acc[nt][r];
  }
  if (lo == 0) {
#pragma unroll
    for (int r = 0; r < 4; ++r)
      plsum[((size_t)b * SEQ + rowq + r) * NSPLIT + sp] = lsum[r];
  }
}

// ---------------- combine: out = sum(pacc)/sum(plsum) -----------------------
__global__ __launch_bounds__(256) void comb_kernel(
    const float* __restrict__ pacc, const float* __restrict__ plsum,
    float* __restrict__ out) {
  const int idx = blockIdx.x * 256 + threadIdx.x;   // 0 .. ROWS*16-1
  const int row = idx >> 4;
  const int h4 = (idx & 15) << 2;
  const float* pa = pacc + (size_t)row * (NSPLIT * HD) + h4;
  float4 s = make_float4(0.f, 0.f, 0.f, 0.f);
  float d = 0.f;
#pragma unroll
  for (int sp = 0; sp < NSPLIT; ++sp) {
    const float4 v = *(const float4*)(pa + sp * HD);
    s.x += v.x; s.y += v.y; s.z += v.z; s.w += v.w;
    d += plsum[(size_t)row * NSPLIT + sp];
  }
  const float inv = 1.0f / d;
  float4 o = make_float4(s.x * inv, s.y * inv, s.z * inv, s.w * inv);
  *(float4*)(out + (size_t)row * HD + h4) = o;
}

extern "C" void kernel_launch(void* const* d_in, const int* in_sizes, int n_in,
                              void* d_out, int out_size, void* d_ws, size_t ws_size,
                              hipStream_t stream) {
  const float* x  = (const float*)d_in[0];
  const float* Wq = (const float*)d_in[1];
  const float* Wk = (const float*)d_in[2];
  const float* Wv = (const float*)d_in[3];
  float* out = (float*)d_out;
  short* ws = (short*)d_ws;
  short* qbp = ws;
  short* kbp = ws + (size_t)ROWS * HD;
  short* vtp = ws + (size_t)2 * ROWS * HD;
  short* Wd  = ws + (size_t)3 * ROWS * HD;          // 24576*8 shorts (384 KB)
  float* pacc  = (float*)(ws + (size_t)3 * ROWS * HD + 196608);  // 33.6 MB
  float* plsum = pacc + (size_t)ROWS * NSPLIT * HD;              // 512 KB

  wt_kernel<<<dim3(96), 256, 0, stream>>>(Wq, Wk, Wv, Wd);
  proj_kernel<<<dim3(ROWS / 32), 256, 0, stream>>>(x, Wd, qbp, kbp, vtp);
  attn_kernel<<<dim3(128 * 2 * BATCH), 256, 0, stream>>>(qbp, kbp, vtp, pacc, plsum);
  comb_kernel<<<dim3(ROWS * 16 / 256), 256, 0, stream>>>(pacc, plsum, out);
}